// Round 9
// baseline (243.286 us; speedup 1.0000x reference)
//
#include <hip/hip_runtime.h>
#include <stdint.h>
#include <math.h>

typedef __bf16 bf16;
typedef __attribute__((ext_vector_type(8))) __bf16 bf16x8;
typedef __attribute__((ext_vector_type(4))) __bf16 bf16x4;
typedef __attribute__((ext_vector_type(4))) float f32x4;

#define MFMA_BF16(a, b, c) __builtin_amdgcn_mfma_f32_16x16x32_bf16((a), (b), (c), 0, 0, 0)

#if __has_builtin(__builtin_amdgcn_exp2f)
#define EXP2F __builtin_amdgcn_exp2f
#else
#define EXP2F exp2f
#endif

// scale = 1/sqrt(64) * log2(e): folded into Q so softmax = exp2(s)
#define QSCALE 0.18033688011112042f

// async global->LDS, 16B per lane. LDS dest must be linear in lane order.
__device__ __forceinline__ void gl_lds16(const bf16* g, bf16* l) {
  __builtin_amdgcn_global_load_lds(
      (__attribute__((address_space(1))) unsigned int*)(uintptr_t)(g),
      (__attribute__((address_space(3))) unsigned int*)(l),
      16, 0, 0);
}

// ---------------------------------------------------------------------------
// prep: blocks [0,6144): fp32->bf16 convert of q,k,v (8 elems/thread).
//       blocks [6144,7168): weight transpose+convert dst[n][k]=(bf16)src[k][n].
//       blocks [7168,8192): kpe fp32->bf16 convert (same [h][d][t] layout).
// (bf16 A round-trip kept deliberately: round 5 measured fp32-direct as +50us.)
// ---------------------------------------------------------------------------
__global__ __launch_bounds__(256) void prep(
    const float* __restrict__ q, const float* __restrict__ k,
    const float* __restrict__ v, bf16* __restrict__ qb,
    bf16* __restrict__ kb, bf16* __restrict__ vb,
    const float* __restrict__ W0, const float* __restrict__ W1,
    const float* __restrict__ W2, const float* __restrict__ W3,
    bf16* __restrict__ Wt,
    const float* __restrict__ kpe, bf16* __restrict__ kpeb)
{
  __shared__ float tile[64][65];
  const int tid = threadIdx.x;
  const int bid = blockIdx.x;
  if (bid < 6144) {
    const int z = bid >> 11;            // 2048 blocks per tensor
    const int idx = bid & 2047;
    const float* s = (z == 0) ? q : (z == 1) ? k : v;
    bf16* d = (z == 0) ? qb : (z == 1) ? kb : vb;
    size_t i = ((size_t)idx * 256 + tid) * 8;
    float4 a = *(const float4*)(s + i);
    float4 b = *(const float4*)(s + i + 4);
    bf16x8 o;
    o[0] = (bf16)a.x; o[1] = (bf16)a.y; o[2] = (bf16)a.z; o[3] = (bf16)a.w;
    o[4] = (bf16)b.x; o[5] = (bf16)b.y; o[6] = (bf16)b.z; o[7] = (bf16)b.w;
    *(bf16x8*)(d + i) = o;
  } else if (bid < 7168) {
    const int t = bid - 6144;
    const int z = t >> 8;
    const int rem = t & 255;
    const int r0 = (rem >> 4) * 64, c0 = (rem & 15) * 64;
    const float* src = (z == 0) ? W0 : (z == 1) ? W1 : (z == 2) ? W2 : W3;
    bf16* dst = Wt + (size_t)z * (1024 * 1024);
#pragma unroll
    for (int h = 0; h < 2; ++h) {
      int qq = tid + h * 256;
      int row = qq >> 3, cc = qq & 7;
      float4 a = *(const float4*)(src + (size_t)(r0 + row) * 1024 + c0 + cc * 8);
      float4 b = *(const float4*)(src + (size_t)(r0 + row) * 1024 + c0 + cc * 8 + 4);
      tile[row][cc * 8 + 0] = a.x; tile[row][cc * 8 + 1] = a.y;
      tile[row][cc * 8 + 2] = a.z; tile[row][cc * 8 + 3] = a.w;
      tile[row][cc * 8 + 4] = b.x; tile[row][cc * 8 + 5] = b.y;
      tile[row][cc * 8 + 6] = b.z; tile[row][cc * 8 + 7] = b.w;
    }
    __syncthreads();
#pragma unroll
    for (int h = 0; h < 2; ++h) {
      int qq = tid + h * 256;
      int row = qq >> 3, cc = qq & 7;
      bf16x8 o;
#pragma unroll
      for (int e = 0; e < 8; ++e) o[e] = (bf16)tile[cc * 8 + e][row];
      *(bf16x8*)(dst + (size_t)(c0 + row) * 1024 + r0 + cc * 8) = o;
    }
  } else {
    const int idx = bid - 7168;
    size_t i = ((size_t)idx * 256 + tid) * 8;
    float4 a = *(const float4*)(kpe + i);
    float4 b = *(const float4*)(kpe + i + 4);
    bf16x8 o;
    o[0] = (bf16)a.x; o[1] = (bf16)a.y; o[2] = (bf16)a.z; o[3] = (bf16)a.w;
    o[4] = (bf16)b.x; o[5] = (bf16)b.y; o[6] = (bf16)b.z; o[7] = (bf16)b.w;
    *(bf16x8*)(kpeb + i) = o;
  }
}

// ---------------------------------------------------------------------------
// qkv GEMM, 256x256 tile (round-8 form, unchanged): 8 waves, BK=32, dist-2
// pipeline, counted vmcnt(8), raw s_barrier pairs, XCD swizzle.
// ---------------------------------------------------------------------------
template <int MODE>
__device__ __forceinline__ void gemm_body256(
    const bf16* __restrict__ A, const bf16* __restrict__ Wt,
    const float* __restrict__ bias, float oscale,
    const bf16* __restrict__ kpeb, void* __restrict__ out_v,
    bf16* __restrict__ As, bf16* __restrict__ Bs)
{
  const int tid = threadIdx.x;
  const int w = tid >> 6, lane = tid & 63;
  const int lm = lane & 15, quad = lane >> 4;
  const int wr = w >> 1, wc = w & 1;     // 4 m-waves x 2 n-waves
  const int lid = blockIdx.x + (blockIdx.y << 2);
  const int xcd = lid & 7, jj = lid >> 3;
  const int m0 = (xcd * 2 + (jj & 1)) * 256;
  const int n0 = (jj >> 1) * 256;

  f32x4 zero4 = {0.f, 0.f, 0.f, 0.f};
  f32x4 acc[4][8];
#pragma unroll
  for (int i = 0; i < 4; ++i)
#pragma unroll
    for (int j = 0; j < 8; ++j) acc[i][j] = zero4;

  auto stage = [&](int buf, int kb) {
#pragma unroll
    for (int h = 0; h < 2; ++h) {
      int qq = tid + h * 512;            // 1024 chunks: 256 rows x 4
      int row = qq >> 2, cs = qq & 3;
      int cc = cs ^ ((row >> 1) & 3);
      gl_lds16(A + (size_t)(m0 + row) * 1024 + kb * 32 + cc * 8,
               As + buf * 8192 + qq * 8);
      gl_lds16(Wt + (size_t)(n0 + row) * 1024 + kb * 32 + cc * 8,
               Bs + buf * 8192 + qq * 8);
    }
  };

  stage(0, 0);
  stage(1, 1);

  int cur = 0;
  for (int kb = 0; kb < 32; ++kb) {
    if (kb < 30) {
      stage((kb + 2) % 3, kb + 2);
      asm volatile("s_waitcnt vmcnt(8)" ::: "memory");
    } else if (kb == 30) {
      asm volatile("s_waitcnt vmcnt(4)" ::: "memory");
    } else {
      asm volatile("s_waitcnt vmcnt(0)" ::: "memory");
    }
    __builtin_amdgcn_s_barrier();        // everyone's stage-kb data in LDS
    asm volatile("" ::: "memory");

    const bf16* Ab = As + cur * 8192;
    const bf16* Bb = Bs + cur * 8192;
    bf16x8 af[4], bfv[8];
#pragma unroll
    for (int i = 0; i < 4; ++i) {
      int row = wr * 64 + i * 16 + lm;
      af[i] = *(const bf16x8*)(Ab + row * 32 + ((quad ^ ((row >> 1) & 3)) * 8));
    }
#pragma unroll
    for (int j = 0; j < 8; ++j) {
      int row = wc * 128 + j * 16 + lm;
      bfv[j] = *(const bf16x8*)(Bb + row * 32 + ((quad ^ ((row >> 1) & 3)) * 8));
    }
#pragma unroll
    for (int i = 0; i < 4; ++i)
#pragma unroll
      for (int j = 0; j < 8; ++j)
        acc[i][j] = MFMA_BF16(af[i], bfv[j], acc[i][j]);

    __builtin_amdgcn_s_barrier();        // all reads of buf[cur] done
    asm volatile("" ::: "memory");
    cur = (cur + 1) == 3 ? 0 : cur + 1;
  }

  // epilogue: C/D layout col=lane&15, row=quad*4+reg
  const int ncol = n0 + wc * 128;
  float bv8[8];
#pragma unroll
  for (int j = 0; j < 8; ++j) bv8[j] = bias[ncol + j * 16 + lm];
#pragma unroll
  for (int i = 0; i < 4; ++i) {
    const int mbase = m0 + wr * 64 + i * 16 + quad * 4;  // 4 consecutive rows
    const int b = mbase >> 11, s = mbase & 2047;         // s..s+3 same batch
#pragma unroll
    for (int j = 0; j < 8; ++j) {
      const int ng = ncol + j * 16 + lm;
      const int hh = ng >> 6, d = ng & 63;
      if (MODE == 2) {
        bf16x4 o;
#pragma unroll
        for (int r = 0; r < 4; ++r) o[r] = (bf16)(acc[i][j][r] + bv8[j]);
        *(bf16x4*)((bf16*)out_v + ((size_t)(b * 16 + hh) * 64 + d) * 2048 + s) = o;
      } else if (MODE == 1) {
        bf16x4 p4 = *(const bf16x4*)(kpeb + ((size_t)(hh * 64 + d)) * 2048 + s);
#pragma unroll
        for (int r = 0; r < 4; ++r) {
          float val = acc[i][j][r] + bv8[j] + (float)p4[r];
          ((bf16*)out_v)[(((size_t)(b * 16 + hh)) * 2048 + (s + r)) * 64 + d] =
              (bf16)val;
        }
      } else {  // MODE 0
#pragma unroll
        for (int r = 0; r < 4; ++r) {
          float val = acc[i][j][r] + bv8[j];
          ((bf16*)out_v)[(((size_t)(b * 16 + hh)) * 2048 + (s + r)) * 64 + d] =
              (bf16)(val * oscale);
        }
      }
    }
  }
}

__global__ __launch_bounds__(512, 2) void qkv_gemm(
    const bf16* __restrict__ qb, const bf16* __restrict__ kb, const bf16* __restrict__ vb,
    const bf16* __restrict__ Wt, const float* __restrict__ biq,
    const float* __restrict__ bik, const float* __restrict__ biv,
    const bf16* __restrict__ kpeb,
    bf16* __restrict__ Qs, bf16* __restrict__ Ks, bf16* __restrict__ Vts)
{
  __shared__ __align__(16) bf16 As[3 * 256 * 32];  // 48 KB, 3-deep
  __shared__ __align__(16) bf16 Bs[3 * 256 * 32];  // 48 KB, 3-deep
  const int z = blockIdx.z;
  if (z == 0) {
    gemm_body256<0>(qb, Wt, biq, QSCALE, nullptr, Qs, As, Bs);
  } else if (z == 1) {
    gemm_body256<1>(kb, Wt + (size_t)1 * 1024 * 1024, bik, 1.f, kpeb, Ks, As, Bs);
  } else {
    gemm_body256<2>(vb, Wt + (size_t)2 * 1024 * 1024, biv, 1.f, nullptr, Vts, As, Bs);
  }
}

// ---------------------------------------------------------------------------
// out GEMM (128² tile, 4 waves, dist-2 pipeline + XCD swizzle — round-7 form).
// ---------------------------------------------------------------------------
__global__ __launch_bounds__(256) void out_gemm(
    const bf16* __restrict__ A, const bf16* __restrict__ Wt,
    const float* __restrict__ bias, float* __restrict__ out)
{
  __shared__ __align__(16) bf16 As[3 * 128 * 32];
  __shared__ __align__(16) bf16 Bs[3 * 128 * 32];
  const int tid = threadIdx.x;
  const int w = tid >> 6, lane = tid & 63;
  const int lm = lane & 15, quad = lane >> 4;
  const int wr = w >> 1, wc = w & 1;
  const int lid = blockIdx.x + (blockIdx.y << 3);
  const int xcd = lid & 7, j = lid >> 3;
  const int m0 = (xcd * 4 + (j & 3)) * 128;
  const int n0 = (j >> 2) * 128;

  f32x4 zero4 = {0.f, 0.f, 0.f, 0.f};
  f32x4 acc[4][4];
#pragma unroll
  for (int i = 0; i < 4; ++i)
#pragma unroll
    for (int jj = 0; jj < 4; ++jj) acc[i][jj] = zero4;

  auto stage = [&](int buf, int kb) {
#pragma unroll
    for (int h = 0; h < 2; ++h) {
      int qq = tid + h * 256;
      int row = qq >> 2, cs = qq & 3;
      int cc = cs ^ ((row >> 1) & 3);
      gl_lds16(A + (size_t)(m0 + row) * 1024 + kb * 32 + cc * 8,
               As + buf * 4096 + qq * 8);
      gl_lds16(Wt + (size_t)(n0 + row) * 1024 + kb * 32 + cc * 8,
               Bs + buf * 4096 + qq * 8);
    }
  };

  stage(0, 0);
  stage(1, 1);

  int cur = 0;
  for (int kb = 0; kb < 32; ++kb) {
    if (kb < 30) {
      stage((kb + 2) % 3, kb + 2);
      asm volatile("s_waitcnt vmcnt(8)" ::: "memory");
    } else if (kb == 30) {
      asm volatile("s_waitcnt vmcnt(4)" ::: "memory");
    } else {
      asm volatile("s_waitcnt vmcnt(0)" ::: "memory");
    }
    __builtin_amdgcn_s_barrier();
    asm volatile("" ::: "memory");

    const bf16* Ab = As + cur * 4096;
    const bf16* Bb = Bs + cur * 4096;
    bf16x8 af[4], bfv[4];
#pragma unroll
    for (int i = 0; i < 4; ++i) {
      int row = wr * 64 + i * 16 + lm;
      af[i] = *(const bf16x8*)(Ab + row * 32 + ((quad ^ ((row >> 1) & 3)) * 8));
    }
#pragma unroll
    for (int jj = 0; jj < 4; ++jj) {
      int row = wc * 64 + jj * 16 + lm;
      bfv[jj] = *(const bf16x8*)(Bb + row * 32 + ((quad ^ ((row >> 1) & 3)) * 8));
    }
#pragma unroll
    for (int i = 0; i < 4; ++i)
#pragma unroll
      for (int jj = 0; jj < 4; ++jj)
        acc[i][jj] = MFMA_BF16(af[i], bfv[jj], acc[i][jj]);

    __builtin_amdgcn_s_barrier();
    asm volatile("" ::: "memory");
    cur = (cur + 1) == 3 ? 0 : cur + 1;
  }

  const int ncol = n0 + wc * 64;
  float bv4[4];
#pragma unroll
  for (int jj = 0; jj < 4; ++jj) bv4[jj] = bias[ncol + jj * 16 + lm];
#pragma unroll
  for (int i = 0; i < 4; ++i) {
    const int mbase = m0 + wr * 64 + i * 16 + quad * 4;
#pragma unroll
    for (int jj = 0; jj < 4; ++jj) {
      const int ng = ncol + jj * 16 + lm;
#pragma unroll
      for (int r = 0; r < 4; ++r) {
        out[(size_t)(mbase + r) * 1024 + ng] = acc[i][jj][r] + bv4[jj];
      }
    }
  }
}

// ---------------------------------------------------------------------------
// Flash attention, LDS-bandwidth-optimized: 4 waves x 32 queries (2 s-column
// tiles per wave), Br=128, Bc=64. Round-8 counters proved flash is LDS-pipe
// bound (FETCH 70->12MB with dur flat; 18 b128/wave/iter for 16 MFMA ~= whole
// kernel duration). Each K/V fragment read now feeds TWO MFMAs (s-tiles A,B):
// 20 b128 + 8 b64 per wave-iter for 32 MFMA -> 1.67x less LDS per MFMA.
// Same no-max softmax, K/V dbuf 1-barrier/iter, Qt/Ps union, setprio, XCD grid.
// ---------------------------------------------------------------------------
__global__ __launch_bounds__(256) void flash_attn(
    const bf16* __restrict__ Q, const bf16* __restrict__ K,
    const bf16* __restrict__ Vt, bf16* __restrict__ O)
{
  __shared__ __align__(16) bf16 QtPs[128 * 72];  // Qt staging (128*64) / Ps
  __shared__ __align__(16) bf16 Kt[2][64 * 64];
  __shared__ __align__(16) bf16 Vs[2][64 * 64];
  bf16* Ps = QtPs;

  const int tid = threadIdx.x;           // 0..255
  const int w = tid >> 6, lane = tid & 63;
  const int lm = lane & 15, quad = lane >> 4;
  const int id = blockIdx.x;
  const int xcd = id & 7, j = id >> 3;
  const int bh = xcd * 4 + (j & 3);
  const int s0 = (j >> 2) * 128;
  const size_t qkbase = (size_t)bh * (2048 * 64);
  const size_t vbase = (size_t)bh * (64 * 2048);

  // stage Q tile [128][64]: 1024 chunks, 4/thread
#pragma unroll
  for (int h = 0; h < 4; ++h) {
    int qq = tid + h * 256;
    int row = qq >> 3, cs = qq & 7;
    int cc = cs ^ (row & 7);
    gl_lds16(Q + qkbase + (size_t)(s0 + row) * 64 + cc * 8, QtPs + qq * 8);
  }
  // stage K/V tile 0: 512 chunks each, 2/thread each
#pragma unroll
  for (int h = 0; h < 2; ++h) {
    int qq = tid + h * 256;
    int row = qq >> 3, cs = qq & 7;
    int cc = cs ^ (row & 7);
    gl_lds16(K + qkbase + (size_t)row * 64 + cc * 8, Kt[0] + qq * 8);
    gl_lds16(Vt + vbase + (size_t)row * 2048 + cc * 8, Vs[0] + qq * 8);
  }
  __syncthreads();

  // Q regs, two s-tiles per wave: rows rA = w*32+lm, rB = rA+16.
  // (rA&7)==(rB&7), so both use the same swizzle index.
  bf16x8 qaA0, qaA1, qaB0, qaB1;
  {
    int rA = w * 32 + lm;
    int sw = rA & 7;
    qaA0 = *(const bf16x8*)(QtPs + rA * 64 + ((quad ^ sw) * 8));
    qaA1 = *(const bf16x8*)(QtPs + rA * 64 + (((quad + 4) ^ sw) * 8));
    qaB0 = *(const bf16x8*)(QtPs + (rA + 16) * 64 + ((quad ^ sw) * 8));
    qaB1 = *(const bf16x8*)(QtPs + (rA + 16) * 64 + (((quad + 4) ^ sw) * 8));
  }
  __syncthreads();  // qa reads done before Ps overwrites the union

  f32x4 zero4 = {0.f, 0.f, 0.f, 0.f};
  float lA = 0.f, lB = 0.f;
  f32x4 oaccA[4], oaccB[4];
#pragma unroll
  for (int dt = 0; dt < 4; ++dt) { oaccA[dt] = zero4; oaccB[dt] = zero4; }

  const int prowA = (w * 32 + lm) * 72;
  const int prowB = prowA + 16 * 72;

  for (int kt = 0; kt < 32; ++kt) {
    const int cur = kt & 1;
    if (kt < 31) {
      const int t1 = (kt + 1) * 64;
#pragma unroll
      for (int h = 0; h < 2; ++h) {
        int qq = tid + h * 256;
        int row = qq >> 3, cs = qq & 7;
        int cc = cs ^ (row & 7);
        gl_lds16(K + qkbase + (size_t)(t1 + row) * 64 + cc * 8, Kt[cur ^ 1] + qq * 8);
        gl_lds16(Vt + vbase + (size_t)row * 2048 + t1 + cc * 8, Vs[cur ^ 1] + qq * 8);
      }
    }

    // St = K·Q^T for both s-tiles: each K fragment feeds 2 MFMA chains.
#pragma unroll
    for (int c = 0; c < 4; ++c) {
      int row = c * 16 + lm;
      bf16x8 kb0 = *(const bf16x8*)(Kt[cur] + row * 64 + ((quad ^ (row & 7)) * 8));
      bf16x8 kb1 = *(const bf16x8*)(Kt[cur] + row * 64 + (((quad + 4) ^ (row & 7)) * 8));
      __builtin_amdgcn_s_setprio(1);
      f32x4 zA = MFMA_BF16(kb0, qaA0, zero4);
      f32x4 stA = MFMA_BF16(kb1, qaA1, zA);
      f32x4 zB = MFMA_BF16(kb0, qaB0, zero4);
      f32x4 stB = MFMA_BF16(kb1, qaB1, zB);
      __builtin_amdgcn_s_setprio(0);
      bf16x4 pkA, pkB;
#pragma unroll
      for (int r = 0; r < 4; ++r) {
        float pA = EXP2F(stA[r]);
        float pB = EXP2F(stB[r]);
        lA += pA; lB += pB;
        pkA[r] = (bf16)pA; pkB[r] = (bf16)pB;
      }
      *(bf16x4*)(Ps + prowA + c * 16 + quad * 4) = pkA;
      *(bf16x4*)(Ps + prowB + c * 16 + quad * 4) = pkB;
    }

    // O^T += V^T·P^T for both s-tiles: each V fragment feeds 2 MFMA chains.
    bf16x8 paA0 = *(const bf16x8*)(Ps + prowA + quad * 8);
    bf16x8 paA1 = *(const bf16x8*)(Ps + prowA + 32 + quad * 8);
    bf16x8 paB0 = *(const bf16x8*)(Ps + prowB + quad * 8);
    bf16x8 paB1 = *(const bf16x8*)(Ps + prowB + 32 + quad * 8);
#pragma unroll
    for (int dt = 0; dt < 4; ++dt) {
      int row = dt * 16 + lm;
      bf16x8 va0 = *(const bf16x8*)(Vs[cur] + row * 64 + ((quad ^ (row & 7)) * 8));
      bf16x8 va1 = *(const bf16x8*)(Vs[cur] + row * 64 + (((quad + 4) ^ (row & 7)) * 8));
      __builtin_amdgcn_s_setprio(1);
      oaccA[dt] = MFMA_BF16(va0, paA0, oaccA[dt]);
      oaccA[dt] = MFMA_BF16(va1, paA1, oaccA[dt]);
      oaccB[dt] = MFMA_BF16(va0, paB0, oaccB[dt]);
      oaccB[dt] = MFMA_BF16(va1, paB1, oaccB[dt]);
      __builtin_amdgcn_s_setprio(0);
    }

    __syncthreads();  // drains prefetch (vmcnt) + fences buffer reads (lgkm)
  }

  // denoms: cross-quad reduce (2 shuffles each), normalize, bounce O^T via Ps
  lA += __shfl_xor(lA, 16, 64);
  lA += __shfl_xor(lA, 32, 64);
  lB += __shfl_xor(lB, 16, 64);
  lB += __shfl_xor(lB, 32, 64);
  float invA = 1.f / lA, invB = 1.f / lB;
#pragma unroll
  for (int dt = 0; dt < 4; ++dt)
#pragma unroll
    for (int r = 0; r < 4; ++r) {
      Ps[prowA + dt * 16 + quad * 4 + r] = (bf16)(oaccA[dt][r] * invA);
      Ps[prowB + dt * 16 + quad * 4 + r] = (bf16)(oaccB[dt][r] * invB);
    }

  const int b = bh >> 4, hh = bh & 15;
  const int srowA = s0 + w * 32 + lm;
  const size_t obA = ((size_t)(b * 2048 + srowA)) * 1024 + hh * 64;
  const size_t obB = ((size_t)(b * 2048 + srowA + 16)) * 1024 + hh * 64;
#pragma unroll
  for (int half = 0; half < 2; ++half) {
    bf16x8 ovA = *(const bf16x8*)(Ps + prowA + (half * 4 + quad) * 8);
    *(bf16x8*)(O + obA + (half * 4 + quad) * 8) = ovA;
    bf16x8 ovB = *(const bf16x8*)(Ps + prowB + (half * 4 + quad) * 8);
    *(bf16x8*)(O + obB + (half * 4 + quad) * 8) = ovB;
  }
}

// ---------------------------------------------------------------------------
extern "C" void kernel_launch(void* const* d_in, const int* in_sizes, int n_in,
                              void* d_out, int out_size, void* d_ws, size_t ws_size,
                              hipStream_t stream) {
  (void)in_sizes; (void)n_in; (void)out_size; (void)ws_size;
  const float* q   = (const float*)d_in[0];
  const float* k   = (const float*)d_in[1];
  const float* v   = (const float*)d_in[2];
  const float* kpe = (const float*)d_in[3];
  const float* Wq  = (const float*)d_in[4];
  const float* bq  = (const float*)d_in[5];
  const float* Wk  = (const float*)d_in[6];
  const float* bk  = (const float*)d_in[7];
  const float* Wv  = (const float*)d_in[8];
  const float* bv  = (const float*)d_in[9];
  const float* Wo  = (const float*)d_in[10];
  const float* bo  = (const float*)d_in[11];

  const size_t NT = 4u * 1024 * 1024;  // 4M elems per [4096,1024] tensor
  bf16* ws  = (bf16*)d_ws;
  bf16* Wt  = ws;            // 4 x 1M elems (bf16 W^T for Wq,Wk,Wv,Wo)
  bf16* qb  = Wt + NT;       // bf16 copies of q,k,v
  bf16* kb  = qb + NT;
  bf16* vb  = kb + NT;
  bf16* Qs  = vb + NT;       // [bh][s][d], pre-scaled
  bf16* Ks  = Qs + NT;       // K_eff = K + kpe^T  [bh][t][d]  (fused in GEMM)
  bf16* Vts = Ks + NT;       // V^T  [bh][d][t]               (fused in GEMM)
  bf16* Oa  = Vts + NT;      // attn out [b][s][h*64+d]
  bf16* kpeb = Oa;           // bf16 kpe [h][d][t]: aliases Oa — consumed by
                             // qkv_gemm before flash_attn writes O there.

  prep<<<dim3(8192), 256, 0, stream>>>(q, k, v, qb, kb, vb, Wq, Wk, Wv, Wo, Wt,
                                       kpe, kpeb);
  qkv_gemm<<<dim3(4, 16, 3), 512, 0, stream>>>(qb, kb, vb, Wt, bq, bk, bv, kpeb,
                                               Qs, Ks, Vts);
  flash_attn<<<dim3(512), 256, 0, stream>>>(Qs, Ks, Vts, Oa);
  out_gemm<<<dim3(8, 32), 256, 0, stream>>>(Oa, Wt + 3u * 1024 * 1024, bo,
                                            (float*)d_out);
}

// Round 10
// 232.739 us; speedup vs baseline: 1.0453x; 1.0453x over previous
//
#include <hip/hip_runtime.h>
#include <stdint.h>
#include <math.h>

typedef __bf16 bf16;
typedef __attribute__((ext_vector_type(8))) __bf16 bf16x8;
typedef __attribute__((ext_vector_type(4))) __bf16 bf16x4;
typedef __attribute__((ext_vector_type(4))) float f32x4;

#define MFMA_BF16(a, b, c) __builtin_amdgcn_mfma_f32_16x16x32_bf16((a), (b), (c), 0, 0, 0)

#if __has_builtin(__builtin_amdgcn_exp2f)
#define EXP2F __builtin_amdgcn_exp2f
#else
#define EXP2F exp2f
#endif

// scale = 1/sqrt(64) * log2(e): folded into Q so softmax = exp2(s)
#define QSCALE 0.18033688011112042f

// async global->LDS, 16B per lane. LDS dest must be linear in lane order.
__device__ __forceinline__ void gl_lds16(const bf16* g, bf16* l) {
  __builtin_amdgcn_global_load_lds(
      (__attribute__((address_space(1))) unsigned int*)(uintptr_t)(g),
      (__attribute__((address_space(3))) unsigned int*)(l),
      16, 0, 0);
}

// ---------------------------------------------------------------------------
// prep: blocks [0,6144): fp32->bf16 convert of q,k,v (8 elems/thread).
//       blocks [6144,7168): weight transpose+convert dst[n][k]=(bf16)src[k][n].
//       blocks [7168,8192): kpe fp32->bf16 convert (same [h][d][t] layout).
// (bf16 A round-trip kept deliberately: round 5 measured fp32-direct as +50us.)
// ---------------------------------------------------------------------------
__global__ __launch_bounds__(256) void prep(
    const float* __restrict__ q, const float* __restrict__ k,
    const float* __restrict__ v, bf16* __restrict__ qb,
    bf16* __restrict__ kb, bf16* __restrict__ vb,
    const float* __restrict__ W0, const float* __restrict__ W1,
    const float* __restrict__ W2, const float* __restrict__ W3,
    bf16* __restrict__ Wt,
    const float* __restrict__ kpe, bf16* __restrict__ kpeb)
{
  __shared__ float tile[64][65];
  const int tid = threadIdx.x;
  const int bid = blockIdx.x;
  if (bid < 6144) {
    const int z = bid >> 11;            // 2048 blocks per tensor
    const int idx = bid & 2047;
    const float* s = (z == 0) ? q : (z == 1) ? k : v;
    bf16* d = (z == 0) ? qb : (z == 1) ? kb : vb;
    size_t i = ((size_t)idx * 256 + tid) * 8;
    float4 a = *(const float4*)(s + i);
    float4 b = *(const float4*)(s + i + 4);
    bf16x8 o;
    o[0] = (bf16)a.x; o[1] = (bf16)a.y; o[2] = (bf16)a.z; o[3] = (bf16)a.w;
    o[4] = (bf16)b.x; o[5] = (bf16)b.y; o[6] = (bf16)b.z; o[7] = (bf16)b.w;
    *(bf16x8*)(d + i) = o;
  } else if (bid < 7168) {
    const int t = bid - 6144;
    const int z = t >> 8;
    const int rem = t & 255;
    const int r0 = (rem >> 4) * 64, c0 = (rem & 15) * 64;
    const float* src = (z == 0) ? W0 : (z == 1) ? W1 : (z == 2) ? W2 : W3;
    bf16* dst = Wt + (size_t)z * (1024 * 1024);
#pragma unroll
    for (int h = 0; h < 2; ++h) {
      int qq = tid + h * 256;
      int row = qq >> 3, cc = qq & 7;
      float4 a = *(const float4*)(src + (size_t)(r0 + row) * 1024 + c0 + cc * 8);
      float4 b = *(const float4*)(src + (size_t)(r0 + row) * 1024 + c0 + cc * 8 + 4);
      tile[row][cc * 8 + 0] = a.x; tile[row][cc * 8 + 1] = a.y;
      tile[row][cc * 8 + 2] = a.z; tile[row][cc * 8 + 3] = a.w;
      tile[row][cc * 8 + 4] = b.x; tile[row][cc * 8 + 5] = b.y;
      tile[row][cc * 8 + 6] = b.z; tile[row][cc * 8 + 7] = b.w;
    }
    __syncthreads();
#pragma unroll
    for (int h = 0; h < 2; ++h) {
      int qq = tid + h * 256;
      int row = qq >> 3, cc = qq & 7;
      bf16x8 o;
#pragma unroll
      for (int e = 0; e < 8; ++e) o[e] = (bf16)tile[cc * 8 + e][row];
      *(bf16x8*)(dst + (size_t)(c0 + row) * 1024 + r0 + cc * 8) = o;
    }
  } else {
    const int idx = bid - 7168;
    size_t i = ((size_t)idx * 256 + tid) * 8;
    float4 a = *(const float4*)(kpe + i);
    float4 b = *(const float4*)(kpe + i + 4);
    bf16x8 o;
    o[0] = (bf16)a.x; o[1] = (bf16)a.y; o[2] = (bf16)a.z; o[3] = (bf16)a.w;
    o[4] = (bf16)b.x; o[5] = (bf16)b.y; o[6] = (bf16)b.z; o[7] = (bf16)b.w;
    *(bf16x8*)(kpeb + i) = o;
  }
}

// ---------------------------------------------------------------------------
// qkv GEMM, 256x256 tile, BK=64: 16 K-steps (half the barriers of r8's BK=32),
// 64 MFMA/wave/step. 2-deep LDS dbuf (128 KB), counted vmcnt(8) — identical
// wait math to the proven r7/r8 loop: stage = 8 loads/thread; at the wait
// point outstanding = 8 (current) + 8 (next, just issued) -> vmcnt(8) drains
// exactly the current step's loads. Staging/swizzle = flash's proven Q-tile
// pattern (row stride 64 elems, cc = cs ^ (row&7); slot g^(row&7) holds chunk
// g). Fragment reads split K into halves h=0,1 to keep VGPR ~200.
// ---------------------------------------------------------------------------
template <int MODE>
__device__ __forceinline__ void gemm_body256(
    const bf16* __restrict__ A, const bf16* __restrict__ Wt,
    const float* __restrict__ bias, float oscale,
    const bf16* __restrict__ kpeb, void* __restrict__ out_v,
    bf16* __restrict__ As, bf16* __restrict__ Bs)
{
  const int tid = threadIdx.x;
  const int w = tid >> 6, lane = tid & 63;
  const int lm = lane & 15, quad = lane >> 4;
  const int wr = w >> 1, wc = w & 1;     // 4 m-waves x 2 n-waves
  const int lid = blockIdx.x + (blockIdx.y << 2);
  const int xcd = lid & 7, jj = lid >> 3;
  const int m0 = (xcd * 2 + (jj & 1)) * 256;
  const int n0 = (jj >> 1) * 256;

  f32x4 zero4 = {0.f, 0.f, 0.f, 0.f};
  f32x4 acc[4][8];
#pragma unroll
  for (int i = 0; i < 4; ++i)
#pragma unroll
    for (int j = 0; j < 8; ++j) acc[i][j] = zero4;

  auto stage = [&](int buf, int kb) {
#pragma unroll
    for (int h = 0; h < 4; ++h) {
      int qq = tid + h * 512;            // 2048 chunks: 256 rows x 8
      int row = qq >> 3, cs = qq & 7;
      int cc = cs ^ (row & 7);
      gl_lds16(A + (size_t)(m0 + row) * 1024 + kb * 64 + cc * 8,
               As + buf * 16384 + qq * 8);
      gl_lds16(Wt + (size_t)(n0 + row) * 1024 + kb * 64 + cc * 8,
               Bs + buf * 16384 + qq * 8);
    }
  };

  stage(0, 0);

  for (int kb = 0; kb < 16; ++kb) {
    const int cur = kb & 1;
    if (kb < 15) {
      stage(cur ^ 1, kb + 1);  // 8 more loads in flight across this compute
      asm volatile("s_waitcnt vmcnt(8)" ::: "memory");
    } else {
      asm volatile("s_waitcnt vmcnt(0)" ::: "memory");
    }
    __builtin_amdgcn_s_barrier();        // everyone's stage-kb data in LDS
    asm volatile("" ::: "memory");

    const bf16* Ab = As + cur * 16384;
    const bf16* Bb = Bs + cur * 16384;
#pragma unroll
    for (int h = 0; h < 2; ++h) {        // two K=32 halves of the K=64 tile
      bf16x8 af[4], bfv[8];
#pragma unroll
      for (int i = 0; i < 4; ++i) {
        int row = wr * 64 + i * 16 + lm;
        af[i] = *(const bf16x8*)(Ab + row * 64 + (((quad + h * 4) ^ (row & 7)) * 8));
      }
#pragma unroll
      for (int j = 0; j < 8; ++j) {
        int row = wc * 128 + j * 16 + lm;
        bfv[j] = *(const bf16x8*)(Bb + row * 64 + (((quad + h * 4) ^ (row & 7)) * 8));
      }
#pragma unroll
      for (int i = 0; i < 4; ++i)
#pragma unroll
        for (int j = 0; j < 8; ++j)
          acc[i][j] = MFMA_BF16(af[i], bfv[j], acc[i][j]);
    }

    __builtin_amdgcn_s_barrier();        // all reads of buf[cur] done
    asm volatile("" ::: "memory");
  }

  // epilogue: C/D layout col=lane&15, row=quad*4+reg
  const int ncol = n0 + wc * 128;
  float bv8[8];
#pragma unroll
  for (int j = 0; j < 8; ++j) bv8[j] = bias[ncol + j * 16 + lm];
#pragma unroll
  for (int i = 0; i < 4; ++i) {
    const int mbase = m0 + wr * 64 + i * 16 + quad * 4;  // 4 consecutive rows
    const int b = mbase >> 11, s = mbase & 2047;         // s..s+3 same batch
#pragma unroll
    for (int j = 0; j < 8; ++j) {
      const int ng = ncol + j * 16 + lm;
      const int hh = ng >> 6, d = ng & 63;
      if (MODE == 2) {
        bf16x4 o;
#pragma unroll
        for (int r = 0; r < 4; ++r) o[r] = (bf16)(acc[i][j][r] + bv8[j]);
        *(bf16x4*)((bf16*)out_v + ((size_t)(b * 16 + hh) * 64 + d) * 2048 + s) = o;
      } else if (MODE == 1) {
        bf16x4 p4 = *(const bf16x4*)(kpeb + ((size_t)(hh * 64 + d)) * 2048 + s);
#pragma unroll
        for (int r = 0; r < 4; ++r) {
          float val = acc[i][j][r] + bv8[j] + (float)p4[r];
          ((bf16*)out_v)[(((size_t)(b * 16 + hh)) * 2048 + (s + r)) * 64 + d] =
              (bf16)val;
        }
      } else {  // MODE 0
#pragma unroll
        for (int r = 0; r < 4; ++r) {
          float val = acc[i][j][r] + bv8[j];
          ((bf16*)out_v)[(((size_t)(b * 16 + hh)) * 2048 + (s + r)) * 64 + d] =
              (bf16)(val * oscale);
        }
      }
    }
  }
}

__global__ __launch_bounds__(512, 2) void qkv_gemm(
    const bf16* __restrict__ qb, const bf16* __restrict__ kb, const bf16* __restrict__ vb,
    const bf16* __restrict__ Wt, const float* __restrict__ biq,
    const float* __restrict__ bik, const float* __restrict__ biv,
    const bf16* __restrict__ kpeb,
    bf16* __restrict__ Qs, bf16* __restrict__ Ks, bf16* __restrict__ Vts)
{
  __shared__ __align__(16) bf16 As[2 * 256 * 64];  // 64 KB, 2-deep, BK=64
  __shared__ __align__(16) bf16 Bs[2 * 256 * 64];  // 64 KB, 2-deep, BK=64
  const int z = blockIdx.z;
  if (z == 0) {
    gemm_body256<0>(qb, Wt, biq, QSCALE, nullptr, Qs, As, Bs);
  } else if (z == 1) {
    gemm_body256<1>(kb, Wt + (size_t)1 * 1024 * 1024, bik, 1.f, kpeb, Ks, As, Bs);
  } else {
    gemm_body256<2>(vb, Wt + (size_t)2 * 1024 * 1024, biv, 1.f, nullptr, Vts, As, Bs);
  }
}

// ---------------------------------------------------------------------------
// out GEMM (128² tile, 4 waves, dist-2 pipeline + XCD swizzle — round-7 form).
// ---------------------------------------------------------------------------
__global__ __launch_bounds__(256) void out_gemm(
    const bf16* __restrict__ A, const bf16* __restrict__ Wt,
    const float* __restrict__ bias, float* __restrict__ out)
{
  __shared__ __align__(16) bf16 As[3 * 128 * 32];
  __shared__ __align__(16) bf16 Bs[3 * 128 * 32];
  const int tid = threadIdx.x;
  const int w = tid >> 6, lane = tid & 63;
  const int lm = lane & 15, quad = lane >> 4;
  const int wr = w >> 1, wc = w & 1;
  const int lid = blockIdx.x + (blockIdx.y << 3);
  const int xcd = lid & 7, j = lid >> 3;
  const int m0 = (xcd * 4 + (j & 3)) * 128;
  const int n0 = (j >> 2) * 128;

  f32x4 zero4 = {0.f, 0.f, 0.f, 0.f};
  f32x4 acc[4][4];
#pragma unroll
  for (int i = 0; i < 4; ++i)
#pragma unroll
    for (int jj = 0; jj < 4; ++jj) acc[i][jj] = zero4;

  auto stage = [&](int buf, int kb) {
#pragma unroll
    for (int h = 0; h < 2; ++h) {
      int qq = tid + h * 256;
      int row = qq >> 2, cs = qq & 3;
      int cc = cs ^ ((row >> 1) & 3);
      gl_lds16(A + (size_t)(m0 + row) * 1024 + kb * 32 + cc * 8,
               As + buf * 4096 + qq * 8);
      gl_lds16(Wt + (size_t)(n0 + row) * 1024 + kb * 32 + cc * 8,
               Bs + buf * 4096 + qq * 8);
    }
  };

  stage(0, 0);
  stage(1, 1);

  int cur = 0;
  for (int kb = 0; kb < 32; ++kb) {
    if (kb < 30) {
      stage((kb + 2) % 3, kb + 2);
      asm volatile("s_waitcnt vmcnt(8)" ::: "memory");
    } else if (kb == 30) {
      asm volatile("s_waitcnt vmcnt(4)" ::: "memory");
    } else {
      asm volatile("s_waitcnt vmcnt(0)" ::: "memory");
    }
    __builtin_amdgcn_s_barrier();
    asm volatile("" ::: "memory");

    const bf16* Ab = As + cur * 4096;
    const bf16* Bb = Bs + cur * 4096;
    bf16x8 af[4], bfv[4];
#pragma unroll
    for (int i = 0; i < 4; ++i) {
      int row = wr * 64 + i * 16 + lm;
      af[i] = *(const bf16x8*)(Ab + row * 32 + ((quad ^ ((row >> 1) & 3)) * 8));
    }
#pragma unroll
    for (int jj = 0; jj < 4; ++jj) {
      int row = wc * 64 + jj * 16 + lm;
      bfv[jj] = *(const bf16x8*)(Bb + row * 32 + ((quad ^ ((row >> 1) & 3)) * 8));
    }
#pragma unroll
    for (int i = 0; i < 4; ++i)
#pragma unroll
      for (int jj = 0; jj < 4; ++jj)
        acc[i][jj] = MFMA_BF16(af[i], bfv[jj], acc[i][jj]);

    __builtin_amdgcn_s_barrier();
    asm volatile("" ::: "memory");
    cur = (cur + 1) == 3 ? 0 : cur + 1;
  }

  const int ncol = n0 + wc * 64;
  float bv4[4];
#pragma unroll
  for (int jj = 0; jj < 4; ++jj) bv4[jj] = bias[ncol + jj * 16 + lm];
#pragma unroll
  for (int i = 0; i < 4; ++i) {
    const int mbase = m0 + wr * 64 + i * 16 + quad * 4;
#pragma unroll
    for (int jj = 0; jj < 4; ++jj) {
      const int ng = ncol + jj * 16 + lm;
#pragma unroll
      for (int r = 0; r < 4; ++r) {
        out[(size_t)(mbase + r) * 1024 + ng] = acc[i][jj][r] + bv4[jj];
      }
    }
  }
}

// ---------------------------------------------------------------------------
// Flash attention (round-8 form, REVERTED from r9's 4-wave variant: r9 proved
// flash is wave-TLP-bound, not LDS-BW-bound — 8 waves/block is the optimum
// measured so far). Transposed-score no-max softmax, Br=128 (8 waves x 16
// queries), Bc=64, K/V dbuf 1-barrier/iter, Qt/Ps LDS union (50 KB, 3
// blocks/CU), setprio around MFMA, XCD-aware 1D grid (id%8=XCD, 4 bh each).
// ---------------------------------------------------------------------------
__global__ __launch_bounds__(512) void flash_attn(
    const bf16* __restrict__ Q, const bf16* __restrict__ K,
    const bf16* __restrict__ Vt, bf16* __restrict__ O)
{
  __shared__ __align__(16) bf16 QtPs[128 * 72];  // Qt staging (128*64) / Ps
  __shared__ __align__(16) bf16 Kt[2][64 * 64];
  __shared__ __align__(16) bf16 Vs[2][64 * 64];
  bf16* Ps = QtPs;

  const int tid = threadIdx.x;
  const int w = tid >> 6, lane = tid & 63;
  const int lm = lane & 15, quad = lane >> 4;
  const int id = blockIdx.x;
  const int xcd = id & 7, j = id >> 3;
  const int bh = xcd * 4 + (j & 3);
  const int s0 = (j >> 2) * 128;
  const size_t qkbase = (size_t)bh * (2048 * 64);
  const size_t vbase = (size_t)bh * (64 * 2048);

#pragma unroll
  for (int h = 0; h < 2; ++h) {
    int qq = tid + h * 512;
    int row = qq >> 3, cs = qq & 7;
    int cc = cs ^ (row & 7);
    gl_lds16(Q + qkbase + (size_t)(s0 + row) * 64 + cc * 8, QtPs + qq * 8);
  }
  {
    int row = tid >> 3, cs = tid & 7;
    int cc = cs ^ (row & 7);
    gl_lds16(K + qkbase + (size_t)row * 64 + cc * 8, Kt[0] + tid * 8);
    gl_lds16(Vt + vbase + (size_t)row * 2048 + cc * 8, Vs[0] + tid * 8);
  }
  __syncthreads();

  bf16x8 qa0, qa1;
  {
    int row = w * 16 + lm;
    qa0 = *(const bf16x8*)(QtPs + row * 64 + ((quad ^ (row & 7)) * 8));
    qa1 = *(const bf16x8*)(QtPs + row * 64 + (((quad + 4) ^ (row & 7)) * 8));
  }
  __syncthreads();  // qa reads done before Ps overwrites the union

  f32x4 zero4 = {0.f, 0.f, 0.f, 0.f};
  float l_part = 0.f;
  f32x4 oacc[4];
#pragma unroll
  for (int dt = 0; dt < 4; ++dt) oacc[dt] = zero4;

  const int prow = (w * 16 + lm) * 72;

  for (int kt = 0; kt < 32; ++kt) {
    const int cur = kt & 1;
    if (kt < 31) {
      const int t1 = (kt + 1) * 64;
      int row = tid >> 3, cs = tid & 7;
      int cc = cs ^ (row & 7);
      gl_lds16(K + qkbase + (size_t)(t1 + row) * 64 + cc * 8, Kt[cur ^ 1] + tid * 8);
      gl_lds16(Vt + vbase + (size_t)row * 2048 + t1 + cc * 8, Vs[cur ^ 1] + tid * 8);
    }

#pragma unroll
    for (int c = 0; c < 4; ++c) {
      int row = c * 16 + lm;
      bf16x8 kb0 = *(const bf16x8*)(Kt[cur] + row * 64 + ((quad ^ (row & 7)) * 8));
      bf16x8 kb1 = *(const bf16x8*)(Kt[cur] + row * 64 + (((quad + 4) ^ (row & 7)) * 8));
      __builtin_amdgcn_s_setprio(1);
      f32x4 z = MFMA_BF16(kb0, qa0, zero4);
      f32x4 st = MFMA_BF16(kb1, qa1, z);
      __builtin_amdgcn_s_setprio(0);
      bf16x4 pk;
#pragma unroll
      for (int r = 0; r < 4; ++r) {
        float p = EXP2F(st[r]);
        l_part += p;
        pk[r] = (bf16)p;
      }
      *(bf16x4*)(Ps + prow + c * 16 + quad * 4) = pk;
    }

    bf16x8 pa0 = *(const bf16x8*)(Ps + prow + quad * 8);
    bf16x8 pa1 = *(const bf16x8*)(Ps + prow + 32 + quad * 8);
#pragma unroll
    for (int dt = 0; dt < 4; ++dt) {
      int row = dt * 16 + lm;
      bf16x8 va0 = *(const bf16x8*)(Vs[cur] + row * 64 + ((quad ^ (row & 7)) * 8));
      bf16x8 va1 = *(const bf16x8*)(Vs[cur] + row * 64 + (((quad + 4) ^ (row & 7)) * 8));
      __builtin_amdgcn_s_setprio(1);
      oacc[dt] = MFMA_BF16(va0, pa0, oacc[dt]);
      oacc[dt] = MFMA_BF16(va1, pa1, oacc[dt]);
      __builtin_amdgcn_s_setprio(0);
    }

    __syncthreads();
  }

  float l = l_part;
  l += __shfl_xor(l, 16, 64);
  l += __shfl_xor(l, 32, 64);
  float inv = 1.f / l;
#pragma unroll
  for (int dt = 0; dt < 4; ++dt)
#pragma unroll
    for (int r = 0; r < 4; ++r)
      Ps[prow + dt * 16 + quad * 4 + r] = (bf16)(oacc[dt][r] * inv);

  const int b = bh >> 4, hh = bh & 15;
  const int srow = s0 + w * 16 + lm;
  const size_t ob = ((size_t)(b * 2048 + srow)) * 1024 + hh * 64;
#pragma unroll
  for (int half = 0; half < 2; ++half) {
    bf16x8 ov = *(const bf16x8*)(Ps + prow + (half * 4 + quad) * 8);
    *(bf16x8*)(O + ob + (half * 4 + quad) * 8) = ov;
  }
}

// ---------------------------------------------------------------------------
extern "C" void kernel_launch(void* const* d_in, const int* in_sizes, int n_in,
                              void* d_out, int out_size, void* d_ws, size_t ws_size,
                              hipStream_t stream) {
  (void)in_sizes; (void)n_in; (void)out_size; (void)ws_size;
  const float* q   = (const float*)d_in[0];
  const float* k   = (const float*)d_in[1];
  const float* v   = (const float*)d_in[2];
  const float* kpe = (const float*)d_in[3];
  const float* Wq  = (const float*)d_in[4];
  const float* bq  = (const float*)d_in[5];
  const float* Wk  = (const float*)d_in[6];
  const float* bk  = (const float*)d_in[7];
  const float* Wv  = (const float*)d_in[8];
  const float* bv  = (const float*)d_in[9];
  const float* Wo  = (const float*)d_in[10];
  const float* bo  = (const float*)d_in[11];

  const size_t NT = 4u * 1024 * 1024;  // 4M elems per [4096,1024] tensor
  bf16* ws  = (bf16*)d_ws;
  bf16* Wt  = ws;            // 4 x 1M elems (bf16 W^T for Wq,Wk,Wv,Wo)
  bf16* qb  = Wt + NT;       // bf16 copies of q,k,v
  bf16* kb  = qb + NT;
  bf16* vb  = kb + NT;
  bf16* Qs  = vb + NT;       // [bh][s][d], pre-scaled
  bf16* Ks  = Qs + NT;       // K_eff = K + kpe^T  [bh][t][d]  (fused in GEMM)
  bf16* Vts = Ks + NT;       // V^T  [bh][d][t]               (fused in GEMM)
  bf16* Oa  = Vts + NT;      // attn out [b][s][h*64+d]
  bf16* kpeb = Oa;           // bf16 kpe [h][d][t]: aliases Oa — consumed by
                             // qkv_gemm before flash_attn writes O there.

  prep<<<dim3(8192), 256, 0, stream>>>(q, k, v, qb, kb, vb, Wq, Wk, Wv, Wo, Wt,
                                       kpe, kpeb);
  qkv_gemm<<<dim3(4, 16, 3), 512, 0, stream>>>(qb, kb, vb, Wt, bq, bk, bv, kpeb,
                                               Qs, Ks, Vts);
  flash_attn<<<dim3(512), 512, 0, stream>>>(Qs, Ks, Vts, Oa);
  out_gemm<<<dim3(8, 32), 256, 0, stream>>>(Oa, Wt + 3u * 1024 * 1024, bo,
                                            (float*)d_out);
}